// Round 6
// baseline (98.636 us; speedup 1.0000x reference)
//
#include <hip/hip_runtime.h>

// Problem constants (fixed by reference setup_inputs)
#define NTRAJ 8
#define NRES  500
#define NBINS 34

// Single fused kernel. grid (NRES), block 512.
//   block  <-> j   (out[t,j,:] is a block-local sum over i)
//   thread <-> i   (single pass; 12 idle lanes in the last wave)
// 500 blocks x 8 waves = 4000 waves (~4 waves/SIMD) for latency hiding.
// Per-thread register accumulation acc[t][c], wave shfl_xor butterfly,
// 8-wave LDS combine -> single writer per output float. No workspace,
// no atomics, no memset, one dispatch.
__global__ __launch_bounds__(512)
void force_all(const float* __restrict__ cb,    // [NTRAJ][NRES][3]
               const float* __restrict__ gw,    // [NRES i][NRES j][NBINS]
               const float* __restrict__ cen,   // [NBINS]
               const float* __restrict__ sig,   // [NBINS]
               float* __restrict__ out)         // [NTRAJ][NRES][3]
{
    const int tid = threadIdx.x;
    const int j   = blockIdx.x;
    const int i   = tid;

    // cb[t,j,:] is block-uniform -> scalar loads
    float xj[NTRAJ], yj[NTRAJ], zj[NTRAJ];
#pragma unroll
    for (int t = 0; t < NTRAJ; ++t) {
        xj[t] = cb[t * (NRES * 3) + j * 3 + 0];
        yj[t] = cb[t * (NRES * 3) + j * 3 + 1];
        zj[t] = cb[t * (NRES * 3) + j * 3 + 2];
    }

    float acc[NTRAJ][3];
#pragma unroll
    for (int t = 0; t < NTRAJ; ++t)
#pragma unroll
        for (int c = 0; c < 3; ++c)
            acc[t][c] = 0.0f;

    if (i < NRES) {
        // geometry: diffs = cb[t,j] - cb[t,i]
        float dx[NTRAJ], dy[NTRAJ], dz[NTRAJ], d[NTRAJ];
#pragma unroll
        for (int t = 0; t < NTRAJ; ++t) {
            dx[t] = xj[t] - cb[t * (NRES * 3) + i * 3 + 0];
            dy[t] = yj[t] - cb[t * (NRES * 3) + i * 3 + 1];
            dz[t] = zj[t] - cb[t * (NRES * 3) + i * 3 + 2];
            const float d2 = dx[t] * dx[t] + dy[t] * dy[t] + dz[t] * dz[t];
            d[t] = fminf(fmaxf(sqrtf(d2), 0.1f), 40.0f);   // clip(.,0.1,40)
        }

        float force[NTRAJ];
#pragma unroll
        for (int t = 0; t < NTRAJ; ++t) force[t] = 0.0f;

        // gw row (i, j): 34 contiguous floats, 8B-aligned -> 17 float2 loads
        const float2* g2 = reinterpret_cast<const float2*>(
            gw + (size_t)i * (NRES * NBINS) + (size_t)j * NBINS);

#pragma unroll
        for (int k = 0; k < NBINS / 2; ++k) {
            const float2 wpair = g2[k];
#pragma unroll
            for (int u = 0; u < 2; ++u) {
                const int b   = 2 * k + u;
                const float w = u ? wpair.y : wpair.x;
                // per-bin constants (b compile-time after unroll)
                const float sv = __builtin_amdgcn_rcpf(sig[b]);   // 1/sigma
                const float s2 = sv * sv;                         // 1/sigma^2
                // exp(-0.5*(dfm/sig)^2) = exp2(dfm^2 * (-0.5*log2(e)/sig^2))
                const float c1 = s2 * -0.72134752044448f;
                const float wb = (w * sv) * s2;                   // w/sigma^3
                const float cc = cen[b];
#pragma unroll
                for (int t = 0; t < NTRAJ; ++t) {
                    const float dfm = d[t] - cc;
                    const float e   = __builtin_amdgcn_exp2f((dfm * c1) * dfm);
                    force[t] = fmaf(-(dfm * wb), e, force[t]);
                }
            }
        }

        // pair_accs = -force * K * diffs / d
#pragma unroll
        for (int t = 0; t < NTRAJ; ++t) {
            const float s = (force[t] * __builtin_amdgcn_rcpf(d[t])) * -150.0f;
            acc[t][0] = s * dx[t];
            acc[t][1] = s * dy[t];
            acc[t][2] = s * dz[t];
        }
    }

    // ---- block reduction: 64-lane shfl_xor butterfly, then 8-wave LDS combine
#pragma unroll
    for (int m = 1; m <= 32; m <<= 1)
#pragma unroll
        for (int t = 0; t < NTRAJ; ++t)
#pragma unroll
            for (int c = 0; c < 3; ++c)
                acc[t][c] += __shfl_xor(acc[t][c], m, 64);

    __shared__ float red[8][NTRAJ * 3];
    const int wv = tid >> 6;
    if ((tid & 63) == 0) {
#pragma unroll
        for (int t = 0; t < NTRAJ; ++t)
#pragma unroll
            for (int c = 0; c < 3; ++c)
                red[wv][t * 3 + c] = acc[t][c];
    }
    __syncthreads();
    if (tid < NTRAJ * 3) {
        float s = 0.0f;
#pragma unroll
        for (int wvv = 0; wvv < 8; ++wvv) s += red[wvv][tid];
        const int t = tid / 3;
        const int c = tid - t * 3;
        out[t * (NRES * 3) + j * 3 + c] = s;    // single writer per output
    }
}

extern "C" void kernel_launch(void* const* d_in, const int* in_sizes, int n_in,
                              void* d_out, int out_size, void* d_ws, size_t ws_size,
                              hipStream_t stream)
{
    const float* cb  = (const float*)d_in[0];   // coords_cb [8,500,3]
    const float* gw  = (const float*)d_in[1];   // gaussian_weights [500,500,34]
    const float* cen = (const float*)d_in[2];   // dist_bin_centres [34]
    const float* sig = (const float*)d_in[3];   // sigmas [34]
    float* out = (float*)d_out;                 // [8,500,3]

    force_all<<<dim3(NRES), 512, 0, stream>>>(cb, gw, cen, sig, out);
}